// Round 17
// baseline (4964.831 us; speedup 1.0000x reference)
//
#include <hip/hip_runtime.h>
#include <hip/hip_bf16.h>

#define NQ 8
#define NC 1024
#define ND 512
#define NROWTOT 32768
#define QOFF 16777216ULL
#define TAU2 0.05f
#define RST 260

typedef short short8 __attribute__((ext_vector_type(8)));
typedef float f32x16 __attribute__((ext_vector_type(16)));

__device__ __forceinline__ unsigned f2bf_u(float f) {
  unsigned u = __float_as_uint(f);
  return (u + 0x7FFFu + ((u >> 16) & 1u)) >> 16;
}
__device__ __forceinline__ void merge_in(float &d1, int &i1, float &d2, int &i2,
                                         float nd, int ni) {
  bool b1 = (nd < d1) || (nd == d1 && ni < i1);
  bool b2 = (nd < d2) || (nd == d2 && ni < i2);
  if (b1) { d2 = d1; i2 = i1; d1 = nd; i1 = ni; }
  else if (b2) { d2 = nd; i2 = ni; }
}

__global__ __launch_bounds__(256) void cbsq_kernel(const float* __restrict__ cbg,
                                                   float* __restrict__ ws) {
  const int tid = threadIdx.x, wv = tid >> 6, lane = tid & 63;
  const int cbase = blockIdx.x * 32 + wv * 8;
  for (int j = 0; j < 8; ++j) {
    const int c = cbase + j;
    const float4* p = reinterpret_cast<const float4*>(cbg + (size_t)c * ND + lane * 8);
    float4 a = p[0], b = p[1];
    float s = a.x*a.x + a.y*a.y + a.z*a.z + a.w*a.w
            + b.x*b.x + b.y*b.y + b.z*b.z + b.w*b.w;
    #pragma unroll
    for (int m = 1; m < 64; m <<= 1) s += __shfl_xor(s, m, 64);
    if (lane == 0) ws[c] = s;
  }
}

__global__ __launch_bounds__(256) void fmt_kernel(const float* __restrict__ cbg,
                                                  unsigned short* __restrict__ Bh,
                                                  unsigned short* __restrict__ Bl) {
  int t = blockIdx.x * 256 + threadIdx.x;   // 524288 total
  int i16 = t & 1023, ks = (t >> 10) & 31, cp = (t >> 15) & 1, q = (t >> 16) & 7;
  int grp = i16 >> 9, col = i16 & 511, c = cp * 512 + col;
  const float* src = cbg + ((size_t)q * NC + c) * ND + ks * 16 + grp * 8;
  float4 a = reinterpret_cast<const float4*>(src)[0];
  float4 b = reinterpret_cast<const float4*>(src)[1];
  float v[8] = {a.x, a.y, a.z, a.w, b.x, b.y, b.z, b.w};
  unsigned short hv[8], lv[8];
  #pragma unroll
  for (int j = 0; j < 8; ++j) {
    unsigned hb = f2bf_u(v[j]);
    float hf = __uint_as_float(hb << 16);
    unsigned lb = f2bf_u(v[j] - hf);
    hv[j] = (unsigned short)hb; lv[j] = (unsigned short)lb;
  }
  size_t dst = (size_t)(t >> 10) * 8192 + (size_t)i16 * 8;
  uint4 wh, wl;
  wh.x = hv[0] | ((unsigned)hv[1] << 16); wh.y = hv[2] | ((unsigned)hv[3] << 16);
  wh.z = hv[4] | ((unsigned)hv[5] << 16); wh.w = hv[6] | ((unsigned)hv[7] << 16);
  wl.x = lv[0] | ((unsigned)lv[1] << 16); wl.y = lv[2] | ((unsigned)lv[3] << 16);
  wl.z = lv[4] | ((unsigned)lv[5] << 16); wl.w = lv[6] | ((unsigned)lv[7] << 16);
  *reinterpret_cast<uint4*>(Bh + dst) = wh;
  *reinterpret_cast<uint4*>(Bl + dst) = wl;
}

__global__ __launch_bounds__(256) void copy_kernel(const float4* __restrict__ src,
                                                   float4* __restrict__ dst) {
  int i = blockIdx.x * 256 + threadIdx.x;
  dst[i] = src[i];
}

// dist: A staged/split in LDS, B via 4-deep register prefetch (named bufs).
__global__ __launch_bounds__(1024) __attribute__((amdgpu_waves_per_eu(4, 4)))
void dist_kernel(const float* __restrict__ resf, const float* __restrict__ cbsq_g,
                 const unsigned short* __restrict__ Bh,
                 const unsigned short* __restrict__ Bl,
                 float* __restrict__ t2d, int* __restrict__ t2i, int q) {
  __shared__ unsigned resH[64 * RST];
  __shared__ unsigned resL[64 * RST];
  __shared__ float mrgd[2][8][64][2];
  __shared__ int   mrgi[2][8][64][2];
  const int tid = threadIdx.x;
  const int w = tid >> 6, l = tid & 63;
  const int n0 = blockIdx.x * 64;
  const int rowbase = (w >> 3) * 32;
  const int colq = (w & 7) * 64;
  union U8 { uint4 q4; short8 s; unsigned u[4]; };

  { // coalesced panel load + hi/lo split
    const float4* src = reinterpret_cast<const float4*>(resf) + (size_t)n0 * 128;
    #pragma unroll
    for (int j = 0; j < 8; ++j) {
      const int idx = j * 1024 + tid;
      float4 v = src[idx];
      const int row = idx >> 7, c4 = idx & 127;
      unsigned h0 = f2bf_u(v.x), g0 = f2bf_u(v.x - __uint_as_float(h0 << 16));
      unsigned h1 = f2bf_u(v.y), g1 = f2bf_u(v.y - __uint_as_float(h1 << 16));
      unsigned h2 = f2bf_u(v.z), g2 = f2bf_u(v.z - __uint_as_float(h2 << 16));
      unsigned h3 = f2bf_u(v.w), g3 = f2bf_u(v.w - __uint_as_float(h3 << 16));
      const int off = row * RST + c4 * 2;
      resH[off]     = h0 | (h1 << 16);
      resH[off + 1] = h2 | (h3 << 16);
      resL[off]     = g0 | (g1 << 16);
      resL[off + 1] = g2 | (g3 << 16);
    }
  }

  int baddr[2];
  #pragma unroll
  for (int t = 0; t < 2; ++t) {
    int i16 = ((l >> 5) << 9) + colq + t * 32 + (l & 31);
    baddr[t] = i16 * 8;
  }
  const int aoff0 = (rowbase + (l & 31)) * RST + ((l >> 5) << 2);
  __syncthreads();

  #pragma unroll 1
  for (int cp = 0; cp < 2; ++cp) {
    f32x16 acc[2];
    #pragma unroll
    for (int t = 0; t < 2; ++t)
      #pragma unroll
      for (int e = 0; e < 16; ++e) acc[t][e] = 0.f;

    const unsigned short* bhc = Bh + (size_t)((q * 2 + cp) * 32) * 8192;
    const unsigned short* blc = Bl + (size_t)((q * 2 + cp) * 32) * 8192;
    float sqv[2];
    #pragma unroll
    for (int t = 0; t < 2; ++t)
      sqv[t] = cbsq_g[q * NC + cp * 512 + colq + t * 32 + (l & 31)];

    uint4 f0[4], f1[4], f2[4], f3[4];

#define LOADB(buf, kk) { \
    const unsigned short* _h = bhc + (size_t)((kk) & 31) * 8192; \
    const unsigned short* _l = blc + (size_t)((kk) & 31) * 8192; \
    buf[0] = *reinterpret_cast<const uint4*>(_h + baddr[0]); \
    buf[1] = *reinterpret_cast<const uint4*>(_h + baddr[1]); \
    buf[2] = *reinterpret_cast<const uint4*>(_l + baddr[0]); \
    buf[3] = *reinterpret_cast<const uint4*>(_l + baddr[1]); }

#define DOSTEP(kk, buf) { \
    U8 Ah, Al; \
    const int _a = aoff0 + (kk) * 8; \
    Ah.q4 = *reinterpret_cast<const uint4*>(&resH[_a]); \
    Al.q4 = *reinterpret_cast<const uint4*>(&resL[_a]); \
    U8 b0h, b1h, b0l, b1l; \
    b0h.q4 = buf[0]; b1h.q4 = buf[1]; b0l.q4 = buf[2]; b1l.q4 = buf[3]; \
    acc[0] = __builtin_amdgcn_mfma_f32_32x32x16_bf16(Ah.s, b0h.s, acc[0], 0, 0, 0); \
    acc[0] = __builtin_amdgcn_mfma_f32_32x32x16_bf16(Al.s, b0h.s, acc[0], 0, 0, 0); \
    acc[0] = __builtin_amdgcn_mfma_f32_32x32x16_bf16(Ah.s, b0l.s, acc[0], 0, 0, 0); \
    acc[1] = __builtin_amdgcn_mfma_f32_32x32x16_bf16(Ah.s, b1h.s, acc[1], 0, 0, 0); \
    acc[1] = __builtin_amdgcn_mfma_f32_32x32x16_bf16(Al.s, b1h.s, acc[1], 0, 0, 0); \
    acc[1] = __builtin_amdgcn_mfma_f32_32x32x16_bf16(Ah.s, b1l.s, acc[1], 0, 0, 0); }

    LOADB(f0, 0); LOADB(f1, 1); LOADB(f2, 2);
    #pragma unroll 1
    for (int ks = 0; ks < 32; ks += 4) {
      LOADB(f3, ks + 3);
      DOSTEP(ks + 0, f0);
      LOADB(f0, ks + 4);
      DOSTEP(ks + 1, f1);
      LOADB(f1, ks + 5);
      DOSTEP(ks + 2, f2);
      LOADB(f2, ks + 6);
      DOSTEP(ks + 3, f3);
    }
#undef LOADB
#undef DOSTEP

    #pragma unroll
    for (int rg2 = 0; rg2 < 16; ++rg2) {
      float d1 = INFINITY, d2 = INFINITY; int i1 = 0x7fffffff, i2 = 0x7fffffff;
      #pragma unroll
      for (int t = 0; t < 2; ++t) {
        int col = cp * 512 + colq + t * 32 + (l & 31);
        float dd = sqv[t] - 2.0f * acc[t][rg2];
        merge_in(d1, i1, d2, i2, dd, col);
      }
      #pragma unroll
      for (int m = 1; m < 32; m <<= 1) {
        float od1 = __shfl_xor(d1, m, 64), od2 = __shfl_xor(d2, m, 64);
        int oi1 = __shfl_xor(i1, m, 64), oi2 = __shfl_xor(i2, m, 64);
        merge_in(d1, i1, d2, i2, od1, oi1);
        merge_in(d1, i1, d2, i2, od2, oi2);
      }
      if ((l & 31) == 0) {
        int h = l >> 5;
        int rr = rowbase + (rg2 & 3) + 8 * (rg2 >> 2) + 4 * h;
        mrgd[cp][w & 7][rr][0] = d1; mrgd[cp][w & 7][rr][1] = d2;
        mrgi[cp][w & 7][rr][0] = i1; mrgi[cp][w & 7][rr][1] = i2;
      }
    }
  }
  __syncthreads();

  if (tid < 64) {
    float d1 = INFINITY, d2 = INFINITY; int i1 = 0x7fffffff, i2 = 0x7fffffff;
    #pragma unroll
    for (int c2 = 0; c2 < 2; ++c2)
      #pragma unroll
      for (int s2 = 0; s2 < 8; ++s2) {
        merge_in(d1, i1, d2, i2, mrgd[c2][s2][tid][0], mrgi[c2][s2][tid][0]);
        merge_in(d1, i1, d2, i2, mrgd[c2][s2][tid][1], mrgi[c2][s2][tid][1]);
      }
    t2d[(size_t)(n0 + tid) * 2 + 0] = d1;
    t2d[(size_t)(n0 + tid) * 2 + 1] = d2;
    t2i[(size_t)(n0 + tid) * 2 + 0] = i1;
    t2i[(size_t)(n0 + tid) * 2 + 1] = i2;
  }
}

// ---- probes: isolate the k-loop. 128 ksteps = 2x a real cp-pair. ----
__global__ __launch_bounds__(1024) __attribute__((amdgpu_waves_per_eu(4, 4)))
void probe_load(const unsigned short* __restrict__ Bh,
                const unsigned short* __restrict__ Bl,
                unsigned* __restrict__ outp) {
  __shared__ unsigned dummy[25600];   // ~100 KB: pin 1 block/CU like dist
  const int tid = threadIdx.x;
  const int w = tid >> 6, l = tid & 63;
  dummy[tid] = tid * 2654435761u;
  __syncthreads();
  const int colq = (w & 7) * 64;
  int baddr[2];
  #pragma unroll
  for (int t = 0; t < 2; ++t) {
    int i16 = ((l >> 5) << 9) + colq + t * 32 + (l & 31);
    baddr[t] = i16 * 8;
  }
  unsigned acc = dummy[(tid * 33) & 25599];
  uint4 f0[4], f1[4], f2[4], f3[4];
#define LB(buf, kk) { \
    const unsigned short* _h = Bh + (size_t)((kk) & 31) * 8192; \
    const unsigned short* _l = Bl + (size_t)((kk) & 31) * 8192; \
    buf[0] = *reinterpret_cast<const uint4*>(_h + baddr[0]); \
    buf[1] = *reinterpret_cast<const uint4*>(_h + baddr[1]); \
    buf[2] = *reinterpret_cast<const uint4*>(_l + baddr[0]); \
    buf[3] = *reinterpret_cast<const uint4*>(_l + baddr[1]); }
#define CONS(buf) { acc ^= buf[0].x ^ buf[1].y ^ buf[2].z ^ buf[3].w; }
  LB(f0, 0); LB(f1, 1); LB(f2, 2);
  #pragma unroll 1
  for (int ks = 0; ks < 128; ks += 4) {
    LB(f3, ks + 3); CONS(f0);
    LB(f0, ks + 4); CONS(f1);
    LB(f1, ks + 5); CONS(f2);
    LB(f2, ks + 6); CONS(f3);
  }
#undef LB
#undef CONS
  if (l == 0) outp[blockIdx.x * 16 + w] = acc;
}

__global__ __launch_bounds__(1024) __attribute__((amdgpu_waves_per_eu(4, 4)))
void probe_full(const unsigned short* __restrict__ Bh,
                const unsigned short* __restrict__ Bl,
                unsigned* __restrict__ outp) {
  __shared__ unsigned dummy[25600];
  const int tid = threadIdx.x;
  const int w = tid >> 6, l = tid & 63;
  union U8 { uint4 q4; short8 s; unsigned u[4]; };
  dummy[tid] = tid * 2654435761u;
  __syncthreads();
  const int colq = (w & 7) * 64;
  int baddr[2];
  #pragma unroll
  for (int t = 0; t < 2; ++t) {
    int i16 = ((l >> 5) << 9) + colq + t * 32 + (l & 31);
    baddr[t] = i16 * 8;
  }
  U8 Ah, Al;
  #pragma unroll
  for (int t = 0; t < 4; ++t) { Ah.u[t] = dummy[(tid + t) & 25599]; Al.u[t] = dummy[(tid * 7 + t) & 25599]; }
  f32x16 acc[2];
  #pragma unroll
  for (int t = 0; t < 2; ++t)
    #pragma unroll
    for (int e = 0; e < 16; ++e) acc[t][e] = 0.f;
  uint4 f0[4], f1[4], f2[4], f3[4];
#define LB(buf, kk) { \
    const unsigned short* _h = Bh + (size_t)((kk) & 31) * 8192; \
    const unsigned short* _l = Bl + (size_t)((kk) & 31) * 8192; \
    buf[0] = *reinterpret_cast<const uint4*>(_h + baddr[0]); \
    buf[1] = *reinterpret_cast<const uint4*>(_h + baddr[1]); \
    buf[2] = *reinterpret_cast<const uint4*>(_l + baddr[0]); \
    buf[3] = *reinterpret_cast<const uint4*>(_l + baddr[1]); }
#define STEP(buf) { \
    U8 b0h, b1h, b0l, b1l; \
    b0h.q4 = buf[0]; b1h.q4 = buf[1]; b0l.q4 = buf[2]; b1l.q4 = buf[3]; \
    acc[0] = __builtin_amdgcn_mfma_f32_32x32x16_bf16(Ah.s, b0h.s, acc[0], 0, 0, 0); \
    acc[0] = __builtin_amdgcn_mfma_f32_32x32x16_bf16(Al.s, b0h.s, acc[0], 0, 0, 0); \
    acc[0] = __builtin_amdgcn_mfma_f32_32x32x16_bf16(Ah.s, b0l.s, acc[0], 0, 0, 0); \
    acc[1] = __builtin_amdgcn_mfma_f32_32x32x16_bf16(Ah.s, b1h.s, acc[1], 0, 0, 0); \
    acc[1] = __builtin_amdgcn_mfma_f32_32x32x16_bf16(Al.s, b1h.s, acc[1], 0, 0, 0); \
    acc[1] = __builtin_amdgcn_mfma_f32_32x32x16_bf16(Ah.s, b1l.s, acc[1], 0, 0, 0); }
  LB(f0, 0); LB(f1, 1); LB(f2, 2);
  #pragma unroll 1
  for (int ks = 0; ks < 128; ks += 4) {
    LB(f3, ks + 3); STEP(f0);
    LB(f0, ks + 4); STEP(f1);
    LB(f1, ks + 5); STEP(f2);
    LB(f2, ks + 6); STEP(f3);
  }
#undef LB
#undef STEP
  if (l == 0) outp[8192 + blockIdx.x * 16 + w] = (unsigned)(acc[0][0] + acc[1][15]);
}

__global__ __launch_bounds__(256) void upd_kernel(
    float* __restrict__ outf, const float* __restrict__ emb,
    const float* __restrict__ cbg, const float* __restrict__ t2d,
    const int* __restrict__ t2i, float* __restrict__ lpart, int q) {
  __shared__ int   fi_sh[64];
  __shared__ int   tlist[64][3];
  __shared__ int   tcount;
  __shared__ float red[256];
  const int tid = threadIdx.x;
  const int w = tid >> 6, l = tid & 63;
  const int n0 = blockIdx.x * 64;

  if (tid == 0) tcount = 0;
  __syncthreads();

  if (tid < 64) {
    float d1 = t2d[(size_t)(n0 + tid) * 2 + 0];
    float d2 = t2d[(size_t)(n0 + tid) * 2 + 1];
    int i1 = t2i[(size_t)(n0 + tid) * 2 + 0];
    int i2 = t2i[(size_t)(n0 + tid) * 2 + 1];
    int fi = i1 < 0 ? 0 : (i1 > NC - 1 ? NC - 1 : i1);
    int ib = i2 < 0 ? 0 : (i2 > NC - 1 ? NC - 1 : i2);
    fi_sh[tid] = fi;
    if (d2 - d1 < TAU2 && ib != fi) {
      int p = atomicAdd(&tcount, 1);
      tlist[p][0] = tid; tlist[p][1] = fi; tlist[p][2] = ib;
    }
  }
  __syncthreads();

  {
    int nt_ = tcount;
    for (int it = w; it < nt_; it += 4) {
      int rr = tlist[it][0], ia = tlist[it][1], ib = tlist[it][2];
      const float4* rp = reinterpret_cast<const float4*>(outf + (size_t)(n0 + rr) * ND + l * 8);
      float4 r0 = rp[0], r1 = rp[1];
      float rv[8] = {r0.x, r0.y, r0.z, r0.w, r1.x, r1.y, r1.z, r1.w};
      double da = 0.0, db = 0.0;
      {
        const float4* cr = reinterpret_cast<const float4*>(
            cbg + ((size_t)q * NC + ia) * ND + l * 8);
        float4 c0 = cr[0], c1 = cr[1];
        float cv[8] = {c0.x,c0.y,c0.z,c0.w,c1.x,c1.y,c1.z,c1.w};
        #pragma unroll
        for (int j = 0; j < 8; ++j) { double e = (double)cv[j] - (double)rv[j]; da += e * e; }
      }
      {
        const float4* cr = reinterpret_cast<const float4*>(
            cbg + ((size_t)q * NC + ib) * ND + l * 8);
        float4 c0 = cr[0], c1 = cr[1];
        float cv[8] = {c0.x,c0.y,c0.z,c0.w,c1.x,c1.y,c1.z,c1.w};
        #pragma unroll
        for (int j = 0; j < 8; ++j) { double e = (double)cv[j] - (double)rv[j]; db += e * e; }
      }
      #pragma unroll
      for (int m = 1; m < 64; m <<= 1) { da += __shfl_xor(da, m, 64); db += __shfl_xor(db, m, 64); }
      if (l == 0 && (db < da || (db == da && ib < ia))) fi_sh[rr] = ib;
    }
  }
  __syncthreads();

  if (tid < 64)
    outf[QOFF + (size_t)(n0 + tid) * NQ + q] = (float)fi_sh[tid];

  {
    const int row = tid >> 2, sg = tid & 3;
    const size_t base = (size_t)(n0 + row) * ND + sg * 128;
    float4* op = reinterpret_cast<float4*>(outf + base);
    const float4* cp4 = reinterpret_cast<const float4*>(
        cbg + ((size_t)q * NC + fi_sh[row]) * ND + sg * 128);
    const float4* ep = reinterpret_cast<const float4*>(emb + base);
    float ls = 0.f;
    #pragma unroll 4
    for (int i = 0; i < 32; ++i) {
      float4 r = op[i], c = cp4[i];
      float4 nr;
      nr.x = r.x - c.x; nr.y = r.y - c.y; nr.z = r.z - c.z; nr.w = r.w - c.w;
      ls += nr.x*nr.x + nr.y*nr.y + nr.z*nr.z + nr.w*nr.w;
      if (q < NQ - 1) {
        op[i] = nr;
      } else {
        float4 e = ep[i];
        float4 qv;
        qv.x = e.x - nr.x; qv.y = e.y - nr.y; qv.z = e.z - nr.z; qv.w = e.w - nr.w;
        op[i] = qv;
      }
    }
    red[tid] = ls;
  }
  __syncthreads();
  for (int s = 128; s > 0; s >>= 1) {
    if (tid < s) red[tid] += red[tid + s];
    __syncthreads();
  }
  if (tid == 0) lpart[blockIdx.x * NQ + q] = red[0];
}

__global__ __launch_bounds__(256) void loss_kernel(const float* __restrict__ lossws,
                                                   int n, float* __restrict__ outf) {
  __shared__ float red[256];
  const int tid = threadIdx.x;
  float s = 0.f;
  for (int i = tid; i < n; i += 256) s += lossws[i];
  red[tid] = s;
  __syncthreads();
  for (int w = 128; w > 0; w >>= 1) {
    if (tid < w) red[tid] += red[tid + w];
    __syncthreads();
  }
  if (tid == 0) outf[QOFF + (size_t)NROWTOT * NQ] = red[0] / 16777216.0f;
}

// ---------------- fallback (round-4 passing kernel) ----------------
#define ROWS 32
#define BK 32
#define CP 512
#define TAU 0.05f

__global__ __launch_bounds__(256, 1) void rvq_fb(
    const float* __restrict__ emb, const float* __restrict__ cbg,
    const float* __restrict__ cbsq, float* __restrict__ lossws,
    float* __restrict__ outf) {
  __shared__ float resT[ND][ROWS];
  __shared__ float cc[BK][CP];
  __shared__ int   idx_sh[ROWS];
  __shared__ float wred[4];

  const int tid = threadIdx.x;
  const int wv = tid >> 6, lane = tid & 63;
  const int rg = wv, cg = lane;
  const int n0 = blockIdx.x * ROWS;

  float qacc[64];
  #pragma unroll
  for (int s = 0; s < 64; ++s) qacc[s] = 0.f;

  {
    const int r = tid & 31, db = tid >> 5;
    const float4* src = reinterpret_cast<const float4*>(emb + (size_t)(n0 + r) * ND + db * 64);
    #pragma unroll
    for (int s = 0; s < 16; ++s) {
      float4 v = src[s];
      int d = db * 64 + s * 4;
      resT[d+0][r] = v.x; resT[d+1][r] = v.y; resT[d+2][r] = v.z; resT[d+3][r] = v.w;
    }
  }
  __syncthreads();

  const int c0l = cg * 8;
  const int swm = (c0l >> 6) << 2;
  const int off0 = c0l ^ swm;
  const int off1 = (c0l + 4) ^ swm;

  for (int q = 0; q < NQ; ++q) {
    const float* cbq = cbg + (size_t)q * NC * ND;
    float bd1[8], bd2[8]; int bi1[8], bi2[8];
    #pragma unroll
    for (int j = 0; j < 8; ++j) { bd1[j]=INFINITY; bd2[j]=INFINITY; bi1[j]=0x7fffffff; bi2[j]=0x7fffffff; }

    for (int cp = 0; cp < 2; ++cp) {
      float acc[8][8];
      #pragma unroll
      for (int a = 0; a < 8; ++a)
        #pragma unroll
        for (int b = 0; b < 8; ++b) acc[a][b] = 0.f;

      for (int kc = 0; kc < ND / BK; ++kc) {
        __syncthreads();
        {
          const int half = tid & 1;
          const int k0 = half * 16;
          #pragma unroll
          for (int it = 0; it < 4; ++it) {
            const int c = (tid >> 1) + it * 128;
            const int pc = c ^ ((c >> 6) << 2);
            const float4* src = reinterpret_cast<const float4*>(
                cbq + (size_t)(cp * CP + c) * ND + kc * BK + half * 16);
            float4 v0 = src[0], v1 = src[1], v2 = src[2], v3 = src[3];
            cc[k0+ 0][pc]=v0.x; cc[k0+ 1][pc]=v0.y; cc[k0+ 2][pc]=v0.z; cc[k0+ 3][pc]=v0.w;
            cc[k0+ 4][pc]=v1.x; cc[k0+ 5][pc]=v1.y; cc[k0+ 6][pc]=v1.z; cc[k0+ 7][pc]=v1.w;
            cc[k0+ 8][pc]=v2.x; cc[k0+ 9][pc]=v2.y; cc[k0+10][pc]=v2.z; cc[k0+11][pc]=v2.w;
            cc[k0+12][pc]=v3.x; cc[k0+13][pc]=v3.y; cc[k0+14][pc]=v3.z; cc[k0+15][pc]=v3.w;
          }
        }
        __syncthreads();

        float tmp[8][8];
        #pragma unroll
        for (int a = 0; a < 8; ++a)
          #pragma unroll
          for (int b = 0; b < 8; ++b) tmp[a][b] = 0.f;

        #pragma unroll
        for (int kk = 0; kk < BK; ++kk) {
          const float4* rp = reinterpret_cast<const float4*>(&resT[kc * BK + kk][rg * 8]);
          float4 r0 = rp[0], r1 = rp[1];
          const float* ccrow = &cc[kk][0];
          float4 c0 = *reinterpret_cast<const float4*>(ccrow + off0);
          float4 c1 = *reinterpret_cast<const float4*>(ccrow + off1);
          float rv[8] = {r0.x, r0.y, r0.z, r0.w, r1.x, r1.y, r1.z, r1.w};
          float cv[8] = {c0.x, c0.y, c0.z, c0.w, c1.x, c1.y, c1.z, c1.w};
          #pragma unroll
          for (int a = 0; a < 8; ++a)
            #pragma unroll
            for (int b = 0; b < 8; ++b)
              tmp[a][b] = fmaf(rv[a], cv[b], tmp[a][b]);
        }
        #pragma unroll
        for (int a = 0; a < 8; ++a)
          #pragma unroll
          for (int b = 0; b < 8; ++b) acc[a][b] += tmp[a][b];
      }

      const float4* qp = reinterpret_cast<const float4*>(cbsq + q * NC + cp * CP + cg * 8);
      float4 s0 = qp[0], s1 = qp[1];
      float sqv[8] = {s0.x, s0.y, s0.z, s0.w, s1.x, s1.y, s1.z, s1.w};
      #pragma unroll
      for (int r = 0; r < 8; ++r) {
        float d1 = INFINITY, d2 = INFINITY; int i1 = 0x7fffffff, i2 = 0x7fffffff;
        #pragma unroll
        for (int j = 0; j < 8; ++j) {
          float dd = sqv[j] - 2.0f * acc[r][j];
          merge_in(d1, i1, d2, i2, dd, cp * CP + cg * 8 + j);
        }
        #pragma unroll
        for (int m = 1; m < 64; m <<= 1) {
          float od1 = __shfl_xor(d1, m, 64), od2 = __shfl_xor(d2, m, 64);
          int oi1 = __shfl_xor(i1, m, 64), oi2 = __shfl_xor(i2, m, 64);
          merge_in(d1, i1, d2, i2, od1, oi1);
          merge_in(d1, i1, d2, i2, od2, oi2);
        }
        merge_in(bd1[r], bi1[r], bd2[r], bi2[r], d1, i1);
        merge_in(bd1[r], bi1[r], bd2[r], bi2[r], d2, i2);
      }
    }

    #pragma unroll 1
    for (int r = 0; r < 8; ++r) {
      int fi = bi1[r];
      if (bd2[r] - bd1[r] < TAU) {
        const int row = rg * 8 + r;
        const int ia = bi1[r], ib = bi2[r];
        double da = 0.0, db2 = 0.0;
        #pragma unroll 1
        for (int t = 0; t < 2; ++t) {
          const int cidx = t ? ib : ia;
          const float* cr = cbq + (size_t)cidx * ND;
          double dot = 0.0, ss = 0.0;
          #pragma unroll
          for (int u = 0; u < 8; ++u) {
            int k = lane * 8 + u;
            double cvv = (double)cr[k];
            double rvv = (double)resT[k][row];
            dot += cvv * rvv; ss += cvv * cvv;
          }
          #pragma unroll
          for (int m = 1; m < 64; m <<= 1) { dot += __shfl_xor(dot, m, 64); ss += __shfl_xor(ss, m, 64); }
          double dd = ss - 2.0 * dot;
          if (t) db2 = dd; else da = dd;
        }
        if (db2 < da || (db2 == da && ib < ia)) fi = ib;
      }
      fi = fi < 0 ? 0 : (fi > NC - 1 ? NC - 1 : fi);
      if (lane == 0) {
        idx_sh[rg * 8 + r] = fi;
        outf[QOFF + (size_t)(n0 + rg * 8 + r) * NQ + q] = (float)fi;
      }
    }
    __syncthreads();

    {
      const int r = tid & 31, db = tid >> 5;
      const float* crow = cbq + (size_t)idx_sh[r] * ND;
      float ls = 0.f;
      #pragma unroll
      for (int s = 0; s < 64; ++s) {
        int d = db * 64 + s;
        float cv = crow[d];
        float nv = resT[d][r] - cv;
        resT[d][r] = nv;
        qacc[s] += cv;
        ls += nv * nv;
      }
      #pragma unroll
      for (int m = 1; m < 64; m <<= 1) ls += __shfl_xor(ls, m, 64);
      if (lane == 0) wred[wv] = ls;
    }
    __syncthreads();
    if (tid == 0) lossws[blockIdx.x * NQ + q] = wred[0] + wred[1] + wred[2] + wred[3];
    __syncthreads();
  }

  {
    const int r = tid & 31, db = tid >> 5;
    #pragma unroll
    for (int g = 0; g < 16; ++g) {
      float4 w2;
      w2.x = qacc[g*4+0]; w2.y = qacc[g*4+1]; w2.z = qacc[g*4+2]; w2.w = qacc[g*4+3];
      *reinterpret_cast<float4*>(outf + (size_t)(n0 + r) * ND + db * 64 + g * 4) = w2;
    }
  }
}

extern "C" void kernel_launch(void* const* d_in, const int* in_sizes, int n_in,
                              void* d_out, int out_size, void* d_ws, size_t ws_size,
                              hipStream_t stream) {
  (void)in_sizes; (void)n_in; (void)out_size;
  const float* emb = (const float*)d_in[0];
  const float* cbg = (const float*)d_in[1];
  float* wsf = (float*)d_ws;
  float* outf = (float*)d_out;

  cbsq_kernel<<<256, 256, 0, stream>>>(cbg, wsf);

  if (ws_size >= (size_t)18 * 1024 * 1024) {
    float* lpart = wsf + 8192;                                   // 4096 floats
    unsigned short* Bh = (unsigned short*)((char*)d_ws + 65536); // 8 MB
    unsigned short* Bl = Bh + 4194304;                           // 8 MB
    float* t2d = (float*)((char*)d_ws + 16842752);               // 256 KB
    int*   t2i = (int*)((char*)d_ws + 17104896);                 // 256 KB
    unsigned* pscr = (unsigned*)((char*)d_ws + 17367040);        // 64 KB probe scratch

    fmt_kernel<<<2048, 256, 0, stream>>>(cbg, Bh, Bl);
    copy_kernel<<<16384, 256, 0, stream>>>((const float4*)emb, (float4*)outf);
    for (int q = 0; q < NQ; ++q) {
      dist_kernel<<<512, 1024, 0, stream>>>(outf, wsf, Bh, Bl, t2d, t2i, q);
      upd_kernel<<<512, 256, 0, stream>>>(outf, emb, cbg, t2d, t2i, lpart, q);
    }
    loss_kernel<<<1, 256, 0, stream>>>(lpart, 4096, outf);
    // diagnostics (write only to ws scratch; removed next round)
    probe_load<<<512, 1024, 0, stream>>>(Bh, Bl, pscr);
    probe_full<<<512, 1024, 0, stream>>>(Bh, Bl, pscr);
  } else {
    rvq_fb<<<1024, 256, 0, stream>>>(emb, cbg, wsf, wsf + 8192, outf);
    loss_kernel<<<1, 256, 0, stream>>>(wsf + 8192, 8192, outf);
  }
}

// Round 18
// 4670.333 us; speedup vs baseline: 1.0631x; 1.0631x over previous
//
#include <hip/hip_runtime.h>
#include <hip/hip_bf16.h>

#define NQ 8
#define NC 1024
#define ND 512
#define NROWTOT 32768
#define QOFF 16777216ULL
#define TAU2 0.05f
#define RST 260

typedef short short8 __attribute__((ext_vector_type(8)));
typedef float f32x16 __attribute__((ext_vector_type(16)));

__device__ __forceinline__ unsigned f2bf_u(float f) {
  unsigned u = __float_as_uint(f);
  return (u + 0x7FFFu + ((u >> 16) & 1u)) >> 16;
}
__device__ __forceinline__ void merge_in(float &d1, int &i1, float &d2, int &i2,
                                         float nd, int ni) {
  bool b1 = (nd < d1) || (nd == d1 && ni < i1);
  bool b2 = (nd < d2) || (nd == d2 && ni < i2);
  if (b1) { d2 = d1; i2 = i1; d1 = nd; i1 = ni; }
  else if (b2) { d2 = nd; i2 = ni; }
}

__global__ __launch_bounds__(256) void cbsq_kernel(const float* __restrict__ cbg,
                                                   float* __restrict__ ws) {
  const int tid = threadIdx.x, wv = tid >> 6, lane = tid & 63;
  const int cbase = blockIdx.x * 32 + wv * 8;
  for (int j = 0; j < 8; ++j) {
    const int c = cbase + j;
    const float4* p = reinterpret_cast<const float4*>(cbg + (size_t)c * ND + lane * 8);
    float4 a = p[0], b = p[1];
    float s = a.x*a.x + a.y*a.y + a.z*a.z + a.w*a.w
            + b.x*b.x + b.y*b.y + b.z*b.z + b.w*b.w;
    #pragma unroll
    for (int m = 1; m < 64; m <<= 1) s += __shfl_xor(s, m, 64);
    if (lane == 0) ws[c] = s;
  }
}

__global__ __launch_bounds__(256) void fmt_kernel(const float* __restrict__ cbg,
                                                  unsigned short* __restrict__ Bh,
                                                  unsigned short* __restrict__ Bl) {
  int t = blockIdx.x * 256 + threadIdx.x;   // 524288 total
  int i16 = t & 1023, ks = (t >> 10) & 31, cp = (t >> 15) & 1, q = (t >> 16) & 7;
  int grp = i16 >> 9, col = i16 & 511, c = cp * 512 + col;
  const float* src = cbg + ((size_t)q * NC + c) * ND + ks * 16 + grp * 8;
  float4 a = reinterpret_cast<const float4*>(src)[0];
  float4 b = reinterpret_cast<const float4*>(src)[1];
  float v[8] = {a.x, a.y, a.z, a.w, b.x, b.y, b.z, b.w};
  unsigned short hv[8], lv[8];
  #pragma unroll
  for (int j = 0; j < 8; ++j) {
    unsigned hb = f2bf_u(v[j]);
    float hf = __uint_as_float(hb << 16);
    unsigned lb = f2bf_u(v[j] - hf);
    hv[j] = (unsigned short)hb; lv[j] = (unsigned short)lb;
  }
  size_t dst = (size_t)(t >> 10) * 8192 + (size_t)i16 * 8;
  uint4 wh, wl;
  wh.x = hv[0] | ((unsigned)hv[1] << 16); wh.y = hv[2] | ((unsigned)hv[3] << 16);
  wh.z = hv[4] | ((unsigned)hv[5] << 16); wh.w = hv[6] | ((unsigned)hv[7] << 16);
  wl.x = lv[0] | ((unsigned)lv[1] << 16); wl.y = lv[2] | ((unsigned)lv[3] << 16);
  wl.z = lv[4] | ((unsigned)lv[5] << 16); wl.w = lv[6] | ((unsigned)lv[7] << 16);
  *reinterpret_cast<uint4*>(Bh + dst) = wh;
  *reinterpret_cast<uint4*>(Bl + dst) = wl;
}

__global__ __launch_bounds__(256) void copy_kernel(const float4* __restrict__ src,
                                                   float4* __restrict__ dst) {
  int i = blockIdx.x * 256 + threadIdx.x;
  dst[i] = src[i];
}

// dist: A staged/split in LDS; B via 4-deep register prefetch whose issue
// order is PINNED with sched_barrier(0) (r17: compiler sank loads to uses,
// collapsing the pipeline -> one L2-latency stall per k-step; VGPR=52).
__global__ __launch_bounds__(1024) __attribute__((amdgpu_waves_per_eu(4, 4)))
void dist_kernel(const float* __restrict__ resf, const float* __restrict__ cbsq_g,
                 const unsigned short* __restrict__ Bh,
                 const unsigned short* __restrict__ Bl,
                 float* __restrict__ t2d, int* __restrict__ t2i, int q) {
  __shared__ unsigned resH[64 * RST];
  __shared__ unsigned resL[64 * RST];
  __shared__ float mrgd[2][8][64][2];
  __shared__ int   mrgi[2][8][64][2];
  const int tid = threadIdx.x;
  const int w = tid >> 6, l = tid & 63;
  const int n0 = blockIdx.x * 64;
  const int rowbase = (w >> 3) * 32;
  const int colq = (w & 7) * 64;
  union U8 { uint4 q4; short8 s; unsigned u[4]; };

  { // coalesced panel load + hi/lo split
    const float4* src = reinterpret_cast<const float4*>(resf) + (size_t)n0 * 128;
    #pragma unroll
    for (int j = 0; j < 8; ++j) {
      const int idx = j * 1024 + tid;
      float4 v = src[idx];
      const int row = idx >> 7, c4 = idx & 127;
      unsigned h0 = f2bf_u(v.x), g0 = f2bf_u(v.x - __uint_as_float(h0 << 16));
      unsigned h1 = f2bf_u(v.y), g1 = f2bf_u(v.y - __uint_as_float(h1 << 16));
      unsigned h2 = f2bf_u(v.z), g2 = f2bf_u(v.z - __uint_as_float(h2 << 16));
      unsigned h3 = f2bf_u(v.w), g3 = f2bf_u(v.w - __uint_as_float(h3 << 16));
      const int off = row * RST + c4 * 2;
      resH[off]     = h0 | (h1 << 16);
      resH[off + 1] = h2 | (h3 << 16);
      resL[off]     = g0 | (g1 << 16);
      resL[off + 1] = g2 | (g3 << 16);
    }
  }

  int baddr[2];
  #pragma unroll
  for (int t = 0; t < 2; ++t) {
    int i16 = ((l >> 5) << 9) + colq + t * 32 + (l & 31);
    baddr[t] = i16 * 8;
  }
  const int aoff0 = (rowbase + (l & 31)) * RST + ((l >> 5) << 2);
  __syncthreads();

  #pragma unroll 1
  for (int cp = 0; cp < 2; ++cp) {
    f32x16 acc[2];
    #pragma unroll
    for (int t = 0; t < 2; ++t)
      #pragma unroll
      for (int e = 0; e < 16; ++e) acc[t][e] = 0.f;

    const unsigned short* bhc = Bh + (size_t)((q * 2 + cp) * 32) * 8192;
    const unsigned short* blc = Bl + (size_t)((q * 2 + cp) * 32) * 8192;
    float sqv[2];
    #pragma unroll
    for (int t = 0; t < 2; ++t)
      sqv[t] = cbsq_g[q * NC + cp * 512 + colq + t * 32 + (l & 31)];

    uint4 f0[4], f1[4], f2[4], f3[4];

#define SB() __builtin_amdgcn_sched_barrier(0)

#define LOADB(buf, kk) { \
    const unsigned short* _h = bhc + (size_t)((kk) & 31) * 8192; \
    const unsigned short* _l = blc + (size_t)((kk) & 31) * 8192; \
    buf[0] = *reinterpret_cast<const uint4*>(_h + baddr[0]); \
    buf[1] = *reinterpret_cast<const uint4*>(_h + baddr[1]); \
    buf[2] = *reinterpret_cast<const uint4*>(_l + baddr[0]); \
    buf[3] = *reinterpret_cast<const uint4*>(_l + baddr[1]); }

#define DOSTEP(kk, buf) { \
    U8 Ah, Al; \
    const int _a = aoff0 + (kk) * 8; \
    Ah.q4 = *reinterpret_cast<const uint4*>(&resH[_a]); \
    Al.q4 = *reinterpret_cast<const uint4*>(&resL[_a]); \
    U8 b0h, b1h, b0l, b1l; \
    b0h.q4 = buf[0]; b1h.q4 = buf[1]; b0l.q4 = buf[2]; b1l.q4 = buf[3]; \
    acc[0] = __builtin_amdgcn_mfma_f32_32x32x16_bf16(Ah.s, b0h.s, acc[0], 0, 0, 0); \
    acc[0] = __builtin_amdgcn_mfma_f32_32x32x16_bf16(Al.s, b0h.s, acc[0], 0, 0, 0); \
    acc[0] = __builtin_amdgcn_mfma_f32_32x32x16_bf16(Ah.s, b0l.s, acc[0], 0, 0, 0); \
    acc[1] = __builtin_amdgcn_mfma_f32_32x32x16_bf16(Ah.s, b1h.s, acc[1], 0, 0, 0); \
    acc[1] = __builtin_amdgcn_mfma_f32_32x32x16_bf16(Al.s, b1h.s, acc[1], 0, 0, 0); \
    acc[1] = __builtin_amdgcn_mfma_f32_32x32x16_bf16(Ah.s, b1l.s, acc[1], 0, 0, 0); }

    LOADB(f0, 0); LOADB(f1, 1); LOADB(f2, 2);
    SB();
    #pragma unroll 1
    for (int ks = 0; ks < 32; ks += 4) {
      LOADB(f3, ks + 3); SB();
      DOSTEP(ks + 0, f0); SB();
      LOADB(f0, ks + 4); SB();
      DOSTEP(ks + 1, f1); SB();
      LOADB(f1, ks + 5); SB();
      DOSTEP(ks + 2, f2); SB();
      LOADB(f2, ks + 6); SB();
      DOSTEP(ks + 3, f3); SB();
    }
#undef LOADB
#undef DOSTEP
#undef SB

    #pragma unroll
    for (int rg2 = 0; rg2 < 16; ++rg2) {
      float d1 = INFINITY, d2 = INFINITY; int i1 = 0x7fffffff, i2 = 0x7fffffff;
      #pragma unroll
      for (int t = 0; t < 2; ++t) {
        int col = cp * 512 + colq + t * 32 + (l & 31);
        float dd = sqv[t] - 2.0f * acc[t][rg2];
        merge_in(d1, i1, d2, i2, dd, col);
      }
      #pragma unroll
      for (int m = 1; m < 32; m <<= 1) {
        float od1 = __shfl_xor(d1, m, 64), od2 = __shfl_xor(d2, m, 64);
        int oi1 = __shfl_xor(i1, m, 64), oi2 = __shfl_xor(i2, m, 64);
        merge_in(d1, i1, d2, i2, od1, oi1);
        merge_in(d1, i1, d2, i2, od2, oi2);
      }
      if ((l & 31) == 0) {
        int h = l >> 5;
        int rr = rowbase + (rg2 & 3) + 8 * (rg2 >> 2) + 4 * h;
        mrgd[cp][w & 7][rr][0] = d1; mrgd[cp][w & 7][rr][1] = d2;
        mrgi[cp][w & 7][rr][0] = i1; mrgi[cp][w & 7][rr][1] = i2;
      }
    }
  }
  __syncthreads();

  if (tid < 64) {
    float d1 = INFINITY, d2 = INFINITY; int i1 = 0x7fffffff, i2 = 0x7fffffff;
    #pragma unroll
    for (int c2 = 0; c2 < 2; ++c2)
      #pragma unroll
      for (int s2 = 0; s2 < 8; ++s2) {
        merge_in(d1, i1, d2, i2, mrgd[c2][s2][tid][0], mrgi[c2][s2][tid][0]);
        merge_in(d1, i1, d2, i2, mrgd[c2][s2][tid][1], mrgi[c2][s2][tid][1]);
      }
    t2d[(size_t)(n0 + tid) * 2 + 0] = d1;
    t2d[(size_t)(n0 + tid) * 2 + 1] = d2;
    t2i[(size_t)(n0 + tid) * 2 + 0] = i1;
    t2i[(size_t)(n0 + tid) * 2 + 1] = i2;
  }
}

__global__ __launch_bounds__(256) void upd_kernel(
    float* __restrict__ outf, const float* __restrict__ emb,
    const float* __restrict__ cbg, const float* __restrict__ t2d,
    const int* __restrict__ t2i, float* __restrict__ lpart, int q) {
  __shared__ int   fi_sh[64];
  __shared__ int   tlist[64][3];
  __shared__ int   tcount;
  __shared__ float red[256];
  const int tid = threadIdx.x;
  const int w = tid >> 6, l = tid & 63;
  const int n0 = blockIdx.x * 64;

  if (tid == 0) tcount = 0;
  __syncthreads();

  if (tid < 64) {
    float d1 = t2d[(size_t)(n0 + tid) * 2 + 0];
    float d2 = t2d[(size_t)(n0 + tid) * 2 + 1];
    int i1 = t2i[(size_t)(n0 + tid) * 2 + 0];
    int i2 = t2i[(size_t)(n0 + tid) * 2 + 1];
    int fi = i1 < 0 ? 0 : (i1 > NC - 1 ? NC - 1 : i1);
    int ib = i2 < 0 ? 0 : (i2 > NC - 1 ? NC - 1 : i2);
    fi_sh[tid] = fi;
    if (d2 - d1 < TAU2 && ib != fi) {
      int p = atomicAdd(&tcount, 1);
      tlist[p][0] = tid; tlist[p][1] = fi; tlist[p][2] = ib;
    }
  }
  __syncthreads();

  {
    int nt_ = tcount;
    for (int it = w; it < nt_; it += 4) {
      int rr = tlist[it][0], ia = tlist[it][1], ib = tlist[it][2];
      const float4* rp = reinterpret_cast<const float4*>(outf + (size_t)(n0 + rr) * ND + l * 8);
      float4 r0 = rp[0], r1 = rp[1];
      float rv[8] = {r0.x, r0.y, r0.z, r0.w, r1.x, r1.y, r1.z, r1.w};
      double da = 0.0, db = 0.0;
      {
        const float4* cr = reinterpret_cast<const float4*>(
            cbg + ((size_t)q * NC + ia) * ND + l * 8);
        float4 c0 = cr[0], c1 = cr[1];
        float cv[8] = {c0.x,c0.y,c0.z,c0.w,c1.x,c1.y,c1.z,c1.w};
        #pragma unroll
        for (int j = 0; j < 8; ++j) { double e = (double)cv[j] - (double)rv[j]; da += e * e; }
      }
      {
        const float4* cr = reinterpret_cast<const float4*>(
            cbg + ((size_t)q * NC + ib) * ND + l * 8);
        float4 c0 = cr[0], c1 = cr[1];
        float cv[8] = {c0.x,c0.y,c0.z,c0.w,c1.x,c1.y,c1.z,c1.w};
        #pragma unroll
        for (int j = 0; j < 8; ++j) { double e = (double)cv[j] - (double)rv[j]; db += e * e; }
      }
      #pragma unroll
      for (int m = 1; m < 64; m <<= 1) { da += __shfl_xor(da, m, 64); db += __shfl_xor(db, m, 64); }
      if (l == 0 && (db < da || (db == da && ib < ia))) fi_sh[rr] = ib;
    }
  }
  __syncthreads();

  if (tid < 64)
    outf[QOFF + (size_t)(n0 + tid) * NQ + q] = (float)fi_sh[tid];

  {
    const int row = tid >> 2, sg = tid & 3;
    const size_t base = (size_t)(n0 + row) * ND + sg * 128;
    float4* op = reinterpret_cast<float4*>(outf + base);
    const float4* cp4 = reinterpret_cast<const float4*>(
        cbg + ((size_t)q * NC + fi_sh[row]) * ND + sg * 128);
    const float4* ep = reinterpret_cast<const float4*>(emb + base);
    float ls = 0.f;
    #pragma unroll 4
    for (int i = 0; i < 32; ++i) {
      float4 r = op[i], c = cp4[i];
      float4 nr;
      nr.x = r.x - c.x; nr.y = r.y - c.y; nr.z = r.z - c.z; nr.w = r.w - c.w;
      ls += nr.x*nr.x + nr.y*nr.y + nr.z*nr.z + nr.w*nr.w;
      if (q < NQ - 1) {
        op[i] = nr;
      } else {
        float4 e = ep[i];
        float4 qv;
        qv.x = e.x - nr.x; qv.y = e.y - nr.y; qv.z = e.z - nr.z; qv.w = e.w - nr.w;
        op[i] = qv;
      }
    }
    red[tid] = ls;
  }
  __syncthreads();
  for (int s = 128; s > 0; s >>= 1) {
    if (tid < s) red[tid] += red[tid + s];
    __syncthreads();
  }
  if (tid == 0) lpart[blockIdx.x * NQ + q] = red[0];
}

__global__ __launch_bounds__(256) void loss_kernel(const float* __restrict__ lossws,
                                                   int n, float* __restrict__ outf) {
  __shared__ float red[256];
  const int tid = threadIdx.x;
  float s = 0.f;
  for (int i = tid; i < n; i += 256) s += lossws[i];
  red[tid] = s;
  __syncthreads();
  for (int w = 128; w > 0; w >>= 1) {
    if (tid < w) red[tid] += red[tid + w];
    __syncthreads();
  }
  if (tid == 0) outf[QOFF + (size_t)NROWTOT * NQ] = red[0] / 16777216.0f;
}

// ---------------- fallback (round-4 passing kernel) ----------------
#define ROWS 32
#define BK 32
#define CP 512
#define TAU 0.05f

__global__ __launch_bounds__(256, 1) void rvq_fb(
    const float* __restrict__ emb, const float* __restrict__ cbg,
    const float* __restrict__ cbsq, float* __restrict__ lossws,
    float* __restrict__ outf) {
  __shared__ float resT[ND][ROWS];
  __shared__ float cc[BK][CP];
  __shared__ int   idx_sh[ROWS];
  __shared__ float wred[4];

  const int tid = threadIdx.x;
  const int wv = tid >> 6, lane = tid & 63;
  const int rg = wv, cg = lane;
  const int n0 = blockIdx.x * ROWS;

  float qacc[64];
  #pragma unroll
  for (int s = 0; s < 64; ++s) qacc[s] = 0.f;

  {
    const int r = tid & 31, db = tid >> 5;
    const float4* src = reinterpret_cast<const float4*>(emb + (size_t)(n0 + r) * ND + db * 64);
    #pragma unroll
    for (int s = 0; s < 16; ++s) {
      float4 v = src[s];
      int d = db * 64 + s * 4;
      resT[d+0][r] = v.x; resT[d+1][r] = v.y; resT[d+2][r] = v.z; resT[d+3][r] = v.w;
    }
  }
  __syncthreads();

  const int c0l = cg * 8;
  const int swm = (c0l >> 6) << 2;
  const int off0 = c0l ^ swm;
  const int off1 = (c0l + 4) ^ swm;

  for (int q = 0; q < NQ; ++q) {
    const float* cbq = cbg + (size_t)q * NC * ND;
    float bd1[8], bd2[8]; int bi1[8], bi2[8];
    #pragma unroll
    for (int j = 0; j < 8; ++j) { bd1[j]=INFINITY; bd2[j]=INFINITY; bi1[j]=0x7fffffff; bi2[j]=0x7fffffff; }

    for (int cp = 0; cp < 2; ++cp) {
      float acc[8][8];
      #pragma unroll
      for (int a = 0; a < 8; ++a)
        #pragma unroll
        for (int b = 0; b < 8; ++b) acc[a][b] = 0.f;

      for (int kc = 0; kc < ND / BK; ++kc) {
        __syncthreads();
        {
          const int half = tid & 1;
          const int k0 = half * 16;
          #pragma unroll
          for (int it = 0; it < 4; ++it) {
            const int c = (tid >> 1) + it * 128;
            const int pc = c ^ ((c >> 6) << 2);
            const float4* src = reinterpret_cast<const float4*>(
                cbq + (size_t)(cp * CP + c) * ND + kc * BK + half * 16);
            float4 v0 = src[0], v1 = src[1], v2 = src[2], v3 = src[3];
            cc[k0+ 0][pc]=v0.x; cc[k0+ 1][pc]=v0.y; cc[k0+ 2][pc]=v0.z; cc[k0+ 3][pc]=v0.w;
            cc[k0+ 4][pc]=v1.x; cc[k0+ 5][pc]=v1.y; cc[k0+ 6][pc]=v1.z; cc[k0+ 7][pc]=v1.w;
            cc[k0+ 8][pc]=v2.x; cc[k0+ 9][pc]=v2.y; cc[k0+10][pc]=v2.z; cc[k0+11][pc]=v2.w;
            cc[k0+12][pc]=v3.x; cc[k0+13][pc]=v3.y; cc[k0+14][pc]=v3.z; cc[k0+15][pc]=v3.w;
          }
        }
        __syncthreads();

        float tmp[8][8];
        #pragma unroll
        for (int a = 0; a < 8; ++a)
          #pragma unroll
          for (int b = 0; b < 8; ++b) tmp[a][b] = 0.f;

        #pragma unroll
        for (int kk = 0; kk < BK; ++kk) {
          const float4* rp = reinterpret_cast<const float4*>(&resT[kc * BK + kk][rg * 8]);
          float4 r0 = rp[0], r1 = rp[1];
          const float* ccrow = &cc[kk][0];
          float4 c0 = *reinterpret_cast<const float4*>(ccrow + off0);
          float4 c1 = *reinterpret_cast<const float4*>(ccrow + off1);
          float rv[8] = {r0.x, r0.y, r0.z, r0.w, r1.x, r1.y, r1.z, r1.w};
          float cv[8] = {c0.x, c0.y, c0.z, c0.w, c1.x, c1.y, c1.z, c1.w};
          #pragma unroll
          for (int a = 0; a < 8; ++a)
            #pragma unroll
            for (int b = 0; b < 8; ++b)
              tmp[a][b] = fmaf(rv[a], cv[b], tmp[a][b]);
        }
        #pragma unroll
        for (int a = 0; a < 8; ++a)
          #pragma unroll
          for (int b = 0; b < 8; ++b) acc[a][b] += tmp[a][b];
      }

      const float4* qp = reinterpret_cast<const float4*>(cbsq + q * NC + cp * CP + cg * 8);
      float4 s0 = qp[0], s1 = qp[1];
      float sqv[8] = {s0.x, s0.y, s0.z, s0.w, s1.x, s1.y, s1.z, s1.w};
      #pragma unroll
      for (int r = 0; r < 8; ++r) {
        float d1 = INFINITY, d2 = INFINITY; int i1 = 0x7fffffff, i2 = 0x7fffffff;
        #pragma unroll
        for (int j = 0; j < 8; ++j) {
          float dd = sqv[j] - 2.0f * acc[r][j];
          merge_in(d1, i1, d2, i2, dd, cp * CP + cg * 8 + j);
        }
        #pragma unroll
        for (int m = 1; m < 64; m <<= 1) {
          float od1 = __shfl_xor(d1, m, 64), od2 = __shfl_xor(d2, m, 64);
          int oi1 = __shfl_xor(i1, m, 64), oi2 = __shfl_xor(i2, m, 64);
          merge_in(d1, i1, d2, i2, od1, oi1);
          merge_in(d1, i1, d2, i2, od2, oi2);
        }
        merge_in(bd1[r], bi1[r], bd2[r], bi2[r], d1, i1);
        merge_in(bd1[r], bi1[r], bd2[r], bi2[r], d2, i2);
      }
    }

    #pragma unroll 1
    for (int r = 0; r < 8; ++r) {
      int fi = bi1[r];
      if (bd2[r] - bd1[r] < TAU) {
        const int row = rg * 8 + r;
        const int ia = bi1[r], ib = bi2[r];
        double da = 0.0, db2 = 0.0;
        #pragma unroll 1
        for (int t = 0; t < 2; ++t) {
          const int cidx = t ? ib : ia;
          const float* cr = cbq + (size_t)cidx * ND;
          double dot = 0.0, ss = 0.0;
          #pragma unroll
          for (int u = 0; u < 8; ++u) {
            int k = lane * 8 + u;
            double cvv = (double)cr[k];
            double rvv = (double)resT[k][row];
            dot += cvv * rvv; ss += cvv * cvv;
          }
          #pragma unroll
          for (int m = 1; m < 64; m <<= 1) { dot += __shfl_xor(dot, m, 64); ss += __shfl_xor(ss, m, 64); }
          double dd = ss - 2.0 * dot;
          if (t) db2 = dd; else da = dd;
        }
        if (db2 < da || (db2 == da && ib < ia)) fi = ib;
      }
      fi = fi < 0 ? 0 : (fi > NC - 1 ? NC - 1 : fi);
      if (lane == 0) {
        idx_sh[rg * 8 + r] = fi;
        outf[QOFF + (size_t)(n0 + rg * 8 + r) * NQ + q] = (float)fi;
      }
    }
    __syncthreads();

    {
      const int r = tid & 31, db = tid >> 5;
      const float* crow = cbq + (size_t)idx_sh[r] * ND;
      float ls = 0.f;
      #pragma unroll
      for (int s = 0; s < 64; ++s) {
        int d = db * 64 + s;
        float cv = crow[d];
        float nv = resT[d][r] - cv;
        resT[d][r] = nv;
        qacc[s] += cv;
        ls += nv * nv;
      }
      #pragma unroll
      for (int m = 1; m < 64; m <<= 1) ls += __shfl_xor(ls, m, 64);
      if (lane == 0) wred[wv] = ls;
    }
    __syncthreads();
    if (tid == 0) lossws[blockIdx.x * NQ + q] = wred[0] + wred[1] + wred[2] + wred[3];
    __syncthreads();
  }

  {
    const int r = tid & 31, db = tid >> 5;
    #pragma unroll
    for (int g = 0; g < 16; ++g) {
      float4 w2;
      w2.x = qacc[g*4+0]; w2.y = qacc[g*4+1]; w2.z = qacc[g*4+2]; w2.w = qacc[g*4+3];
      *reinterpret_cast<float4*>(outf + (size_t)(n0 + r) * ND + db * 64 + g * 4) = w2;
    }
  }
}

extern "C" void kernel_launch(void* const* d_in, const int* in_sizes, int n_in,
                              void* d_out, int out_size, void* d_ws, size_t ws_size,
                              hipStream_t stream) {
  (void)in_sizes; (void)n_in; (void)out_size;
  const float* emb = (const float*)d_in[0];
  const float* cbg = (const float*)d_in[1];
  float* wsf = (float*)d_ws;
  float* outf = (float*)d_out;

  cbsq_kernel<<<256, 256, 0, stream>>>(cbg, wsf);

  if (ws_size >= (size_t)18 * 1024 * 1024) {
    float* lpart = wsf + 8192;                                   // 4096 floats
    unsigned short* Bh = (unsigned short*)((char*)d_ws + 65536); // 8 MB
    unsigned short* Bl = Bh + 4194304;                           // 8 MB
    float* t2d = (float*)((char*)d_ws + 16842752);               // 256 KB
    int*   t2i = (int*)((char*)d_ws + 17104896);                 // 256 KB

    fmt_kernel<<<2048, 256, 0, stream>>>(cbg, Bh, Bl);
    copy_kernel<<<16384, 256, 0, stream>>>((const float4*)emb, (float4*)outf);
    for (int q = 0; q < NQ; ++q) {
      dist_kernel<<<512, 1024, 0, stream>>>(outf, wsf, Bh, Bl, t2d, t2i, q);
      upd_kernel<<<512, 256, 0, stream>>>(outf, emb, cbg, t2d, t2i, lpart, q);
    }
    loss_kernel<<<1, 256, 0, stream>>>(lpart, 4096, outf);
  } else {
    rvq_fb<<<1024, 256, 0, stream>>>(emb, cbg, wsf, wsf + 8192, outf);
    loss_kernel<<<1, 256, 0, stream>>>(wsf + 8192, 8192, outf);
  }
}

// Round 19
// 4541.615 us; speedup vs baseline: 1.0932x; 1.0283x over previous
//
#include <hip/hip_runtime.h>
#include <hip/hip_bf16.h>

#define NQ 8
#define NC 1024
#define ND 512
#define NROWTOT 32768
#define QOFF 16777216ULL
#define TAU2 0.05f
#define RSTP 522

typedef short short8 __attribute__((ext_vector_type(8)));
typedef float f32x16 __attribute__((ext_vector_type(16)));

__device__ __forceinline__ unsigned f2bf_u(float f) {
  unsigned u = __float_as_uint(f);
  return (u + 0x7FFFu + ((u >> 16) & 1u)) >> 16;
}
__device__ __forceinline__ unsigned pack_hl(float x) {
  unsigned hb = f2bf_u(x);
  float hf = __uint_as_float(hb << 16);
  unsigned lb = f2bf_u(x - hf);
  return (hb << 16) | lb;
}
__device__ __forceinline__ void merge_in(float &d1, int &i1, float &d2, int &i2,
                                         float nd, int ni) {
  bool b1 = (nd < d1) || (nd == d1 && ni < i1);
  bool b2 = (nd < d2) || (nd == d2 && ni < i2);
  if (b1) { d2 = d1; i2 = i1; d1 = nd; i1 = ni; }
  else if (b2) { d2 = nd; i2 = ni; }
}

__global__ __launch_bounds__(256) void cbsq_kernel(const float* __restrict__ cbg,
                                                   float* __restrict__ ws) {
  const int tid = threadIdx.x, wv = tid >> 6, lane = tid & 63;
  const int cbase = blockIdx.x * 32 + wv * 8;
  for (int j = 0; j < 8; ++j) {
    const int c = cbase + j;
    const float4* p = reinterpret_cast<const float4*>(cbg + (size_t)c * ND + lane * 8);
    float4 a = p[0], b = p[1];
    float s = a.x*a.x + a.y*a.y + a.z*a.z + a.w*a.w
            + b.x*b.x + b.y*b.y + b.z*b.z + b.w*b.w;
    #pragma unroll
    for (int m = 1; m < 64; m <<= 1) s += __shfl_xor(s, m, 64);
    if (lane == 0) ws[c] = s;
  }
}

__global__ __launch_bounds__(256) void fmt_kernel(const float* __restrict__ cbg,
                                                  unsigned short* __restrict__ Bh,
                                                  unsigned short* __restrict__ Bl) {
  int t = blockIdx.x * 256 + threadIdx.x;   // 524288 total
  int i16 = t & 1023, ks = (t >> 10) & 31, cp = (t >> 15) & 1, q = (t >> 16) & 7;
  int grp = i16 >> 9, col = i16 & 511, c = cp * 512 + col;
  const float* src = cbg + ((size_t)q * NC + c) * ND + ks * 16 + grp * 8;
  float4 a = reinterpret_cast<const float4*>(src)[0];
  float4 b = reinterpret_cast<const float4*>(src)[1];
  float v[8] = {a.x, a.y, a.z, a.w, b.x, b.y, b.z, b.w};
  unsigned short hv[8], lv[8];
  #pragma unroll
  for (int j = 0; j < 8; ++j) {
    unsigned hb = f2bf_u(v[j]);
    float hf = __uint_as_float(hb << 16);
    unsigned lb = f2bf_u(v[j] - hf);
    hv[j] = (unsigned short)hb; lv[j] = (unsigned short)lb;
  }
  size_t dst = (size_t)(t >> 10) * 8192 + (size_t)i16 * 8;
  uint4 wh, wl;
  wh.x = hv[0] | ((unsigned)hv[1] << 16); wh.y = hv[2] | ((unsigned)hv[3] << 16);
  wh.z = hv[4] | ((unsigned)hv[5] << 16); wh.w = hv[6] | ((unsigned)hv[7] << 16);
  wl.x = lv[0] | ((unsigned)lv[1] << 16); wl.y = lv[2] | ((unsigned)lv[3] << 16);
  wl.z = lv[4] | ((unsigned)lv[5] << 16); wl.w = lv[6] | ((unsigned)lv[7] << 16);
  *reinterpret_cast<uint4*>(Bh + dst) = wh;
  *reinterpret_cast<uint4*>(Bl + dst) = wl;
}

__global__ __launch_bounds__(256) void copy_kernel(const float4* __restrict__ src,
                                                   float4* __restrict__ dst) {
  int i = blockIdx.x * 256 + threadIdx.x;
  dst[i] = src[i];
}

// dist: 512 thr / 8 waves / 32 rows / 1024 blocks. A packed hi|lo u32 in LDS
// (67 KB; total ~73 KB -> 2 blocks/CU for cross-block latency overlap).
// 2-deep B prefetch (32 regs) under launch_bounds(512,2) (256-reg cap -> no spill).
__global__ __launch_bounds__(512, 2)
void dist_kernel(const float* __restrict__ resf, const float* __restrict__ cbsq_g,
                 const unsigned short* __restrict__ Bh,
                 const unsigned short* __restrict__ Bl,
                 float* __restrict__ t2d, int* __restrict__ t2i, int q) {
  __shared__ unsigned resP[32 * RSTP];   // 66.8 KB packed hi|lo
  __shared__ float mrgd[2][8][32][2];    // 4 KB
  __shared__ int   mrgi[2][8][32][2];    // 4 KB
  const int tid = threadIdx.x;
  const int w = tid >> 6, l = tid & 63;
  const int n0 = blockIdx.x * 32;
  const int colq = w * 64;
  union U8 { uint4 q4; short8 s; unsigned u[4]; };

  { // coalesced panel load + pack: 32 rows x 128 float4
    const float4* src = reinterpret_cast<const float4*>(resf) + (size_t)n0 * 128;
    #pragma unroll
    for (int j = 0; j < 8; ++j) {
      const int idx = j * 512 + tid;
      float4 v = src[idx];
      const int row = idx >> 7, c4 = idx & 127;
      const int off = row * RSTP + c4 * 4;
      resP[off + 0] = pack_hl(v.x);
      resP[off + 1] = pack_hl(v.y);
      resP[off + 2] = pack_hl(v.z);
      resP[off + 3] = pack_hl(v.w);
    }
  }

  int baddr[2];
  #pragma unroll
  for (int t = 0; t < 2; ++t) {
    int i16 = ((l >> 5) << 9) + colq + t * 32 + (l & 31);
    baddr[t] = i16 * 8;
  }
  const int aoff0 = (l & 31) * RSTP + ((l >> 5) << 3);
  __syncthreads();

  #pragma unroll 1
  for (int cp = 0; cp < 2; ++cp) {
    f32x16 acc[2];
    #pragma unroll
    for (int t = 0; t < 2; ++t)
      #pragma unroll
      for (int e = 0; e < 16; ++e) acc[t][e] = 0.f;

    const unsigned short* bhc = Bh + (size_t)((q * 2 + cp) * 32) * 8192;
    const unsigned short* blc = Bl + (size_t)((q * 2 + cp) * 32) * 8192;
    float sqv[2];
    #pragma unroll
    for (int t = 0; t < 2; ++t)
      sqv[t] = cbsq_g[q * NC + cp * 512 + colq + t * 32 + (l & 31)];

    uint4 fA[4], fB[4];

#define SB() __builtin_amdgcn_sched_barrier(0)

#define LOADB(buf, kk) { \
    const unsigned short* _h = bhc + (size_t)((kk) & 31) * 8192; \
    const unsigned short* _l = blc + (size_t)((kk) & 31) * 8192; \
    buf[0] = *reinterpret_cast<const uint4*>(_h + baddr[0]); \
    buf[1] = *reinterpret_cast<const uint4*>(_h + baddr[1]); \
    buf[2] = *reinterpret_cast<const uint4*>(_l + baddr[0]); \
    buf[3] = *reinterpret_cast<const uint4*>(_l + baddr[1]); }

#define DOSTEP(kk, buf) { \
    uint4 p0 = *reinterpret_cast<const uint4*>(&resP[aoff0 + (kk) * 16]); \
    uint4 p1 = *reinterpret_cast<const uint4*>(&resP[aoff0 + (kk) * 16 + 4]); \
    unsigned pp[8] = {p0.x, p0.y, p0.z, p0.w, p1.x, p1.y, p1.z, p1.w}; \
    U8 Ah, Al; \
    _Pragma("unroll") \
    for (int p2 = 0; p2 < 4; ++p2) { \
      Ah.u[p2] = (pp[2*p2] >> 16) | (pp[2*p2+1] & 0xFFFF0000u); \
      Al.u[p2] = (pp[2*p2] & 0xFFFFu) | (pp[2*p2+1] << 16); \
    } \
    U8 b0h, b1h, b0l, b1l; \
    b0h.q4 = buf[0]; b1h.q4 = buf[1]; b0l.q4 = buf[2]; b1l.q4 = buf[3]; \
    acc[0] = __builtin_amdgcn_mfma_f32_32x32x16_bf16(Ah.s, b0h.s, acc[0], 0, 0, 0); \
    acc[0] = __builtin_amdgcn_mfma_f32_32x32x16_bf16(Al.s, b0h.s, acc[0], 0, 0, 0); \
    acc[0] = __builtin_amdgcn_mfma_f32_32x32x16_bf16(Ah.s, b0l.s, acc[0], 0, 0, 0); \
    acc[1] = __builtin_amdgcn_mfma_f32_32x32x16_bf16(Ah.s, b1h.s, acc[1], 0, 0, 0); \
    acc[1] = __builtin_amdgcn_mfma_f32_32x32x16_bf16(Al.s, b1h.s, acc[1], 0, 0, 0); \
    acc[1] = __builtin_amdgcn_mfma_f32_32x32x16_bf16(Ah.s, b1l.s, acc[1], 0, 0, 0); }

    LOADB(fA, 0);
    SB();
    #pragma unroll 1
    for (int ks = 0; ks < 32; ks += 2) {
      LOADB(fB, ks + 1); SB();
      DOSTEP(ks + 0, fA); SB();
      LOADB(fA, ks + 2); SB();
      DOSTEP(ks + 1, fB); SB();
    }
#undef LOADB
#undef DOSTEP
#undef SB

    #pragma unroll
    for (int rg2 = 0; rg2 < 16; ++rg2) {
      float d1 = INFINITY, d2 = INFINITY; int i1 = 0x7fffffff, i2 = 0x7fffffff;
      #pragma unroll
      for (int t = 0; t < 2; ++t) {
        int col = cp * 512 + colq + t * 32 + (l & 31);
        float dd = sqv[t] - 2.0f * acc[t][rg2];
        merge_in(d1, i1, d2, i2, dd, col);
      }
      #pragma unroll
      for (int m = 1; m < 32; m <<= 1) {
        float od1 = __shfl_xor(d1, m, 64), od2 = __shfl_xor(d2, m, 64);
        int oi1 = __shfl_xor(i1, m, 64), oi2 = __shfl_xor(i2, m, 64);
        merge_in(d1, i1, d2, i2, od1, oi1);
        merge_in(d1, i1, d2, i2, od2, oi2);
      }
      if ((l & 31) == 0) {
        int h = l >> 5;
        int rr = (rg2 & 3) + 8 * (rg2 >> 2) + 4 * h;
        mrgd[cp][w][rr][0] = d1; mrgd[cp][w][rr][1] = d2;
        mrgi[cp][w][rr][0] = i1; mrgi[cp][w][rr][1] = i2;
      }
    }
  }
  __syncthreads();

  if (tid < 32) {
    float d1 = INFINITY, d2 = INFINITY; int i1 = 0x7fffffff, i2 = 0x7fffffff;
    #pragma unroll
    for (int c2 = 0; c2 < 2; ++c2)
      #pragma unroll
      for (int s2 = 0; s2 < 8; ++s2) {
        merge_in(d1, i1, d2, i2, mrgd[c2][s2][tid][0], mrgi[c2][s2][tid][0]);
        merge_in(d1, i1, d2, i2, mrgd[c2][s2][tid][1], mrgi[c2][s2][tid][1]);
      }
    t2d[(size_t)(n0 + tid) * 2 + 0] = d1;
    t2d[(size_t)(n0 + tid) * 2 + 1] = d2;
    t2i[(size_t)(n0 + tid) * 2 + 0] = i1;
    t2i[(size_t)(n0 + tid) * 2 + 1] = i2;
  }
}

__global__ __launch_bounds__(256) void upd_kernel(
    float* __restrict__ outf, const float* __restrict__ emb,
    const float* __restrict__ cbg, const float* __restrict__ t2d,
    const int* __restrict__ t2i, float* __restrict__ lpart, int q) {
  __shared__ int   fi_sh[64];
  __shared__ int   tlist[64][3];
  __shared__ int   tcount;
  __shared__ float red[256];
  const int tid = threadIdx.x;
  const int w = tid >> 6, l = tid & 63;
  const int n0 = blockIdx.x * 64;

  if (tid == 0) tcount = 0;
  __syncthreads();

  if (tid < 64) {
    float d1 = t2d[(size_t)(n0 + tid) * 2 + 0];
    float d2 = t2d[(size_t)(n0 + tid) * 2 + 1];
    int i1 = t2i[(size_t)(n0 + tid) * 2 + 0];
    int i2 = t2i[(size_t)(n0 + tid) * 2 + 1];
    int fi = i1 < 0 ? 0 : (i1 > NC - 1 ? NC - 1 : i1);
    int ib = i2 < 0 ? 0 : (i2 > NC - 1 ? NC - 1 : i2);
    fi_sh[tid] = fi;
    if (d2 - d1 < TAU2 && ib != fi) {
      int p = atomicAdd(&tcount, 1);
      tlist[p][0] = tid; tlist[p][1] = fi; tlist[p][2] = ib;
    }
  }
  __syncthreads();

  {
    int nt_ = tcount;
    for (int it = w; it < nt_; it += 4) {
      int rr = tlist[it][0], ia = tlist[it][1], ib = tlist[it][2];
      const float4* rp = reinterpret_cast<const float4*>(outf + (size_t)(n0 + rr) * ND + l * 8);
      float4 r0 = rp[0], r1 = rp[1];
      float rv[8] = {r0.x, r0.y, r0.z, r0.w, r1.x, r1.y, r1.z, r1.w};
      double da = 0.0, db = 0.0;
      {
        const float4* cr = reinterpret_cast<const float4*>(
            cbg + ((size_t)q * NC + ia) * ND + l * 8);
        float4 c0 = cr[0], c1 = cr[1];
        float cv[8] = {c0.x,c0.y,c0.z,c0.w,c1.x,c1.y,c1.z,c1.w};
        #pragma unroll
        for (int j = 0; j < 8; ++j) { double e = (double)cv[j] - (double)rv[j]; da += e * e; }
      }
      {
        const float4* cr = reinterpret_cast<const float4*>(
            cbg + ((size_t)q * NC + ib) * ND + l * 8);
        float4 c0 = cr[0], c1 = cr[1];
        float cv[8] = {c0.x,c0.y,c0.z,c0.w,c1.x,c1.y,c1.z,c1.w};
        #pragma unroll
        for (int j = 0; j < 8; ++j) { double e = (double)cv[j] - (double)rv[j]; db += e * e; }
      }
      #pragma unroll
      for (int m = 1; m < 64; m <<= 1) { da += __shfl_xor(da, m, 64); db += __shfl_xor(db, m, 64); }
      if (l == 0 && (db < da || (db == da && ib < ia))) fi_sh[rr] = ib;
    }
  }
  __syncthreads();

  if (tid < 64)
    outf[QOFF + (size_t)(n0 + tid) * NQ + q] = (float)fi_sh[tid];

  {
    const int row = tid >> 2, sg = tid & 3;
    const size_t base = (size_t)(n0 + row) * ND + sg * 128;
    float4* op = reinterpret_cast<float4*>(outf + base);
    const float4* cp4 = reinterpret_cast<const float4*>(
        cbg + ((size_t)q * NC + fi_sh[row]) * ND + sg * 128);
    const float4* ep = reinterpret_cast<const float4*>(emb + base);
    float ls = 0.f;
    #pragma unroll 4
    for (int i = 0; i < 32; ++i) {
      float4 r = op[i], c = cp4[i];
      float4 nr;
      nr.x = r.x - c.x; nr.y = r.y - c.y; nr.z = r.z - c.z; nr.w = r.w - c.w;
      ls += nr.x*nr.x + nr.y*nr.y + nr.z*nr.z + nr.w*nr.w;
      if (q < NQ - 1) {
        op[i] = nr;
      } else {
        float4 e = ep[i];
        float4 qv;
        qv.x = e.x - nr.x; qv.y = e.y - nr.y; qv.z = e.z - nr.z; qv.w = e.w - nr.w;
        op[i] = qv;
      }
    }
    red[tid] = ls;
  }
  __syncthreads();
  for (int s = 128; s > 0; s >>= 1) {
    if (tid < s) red[tid] += red[tid + s];
    __syncthreads();
  }
  if (tid == 0) lpart[blockIdx.x * NQ + q] = red[0];
}

__global__ __launch_bounds__(256) void loss_kernel(const float* __restrict__ lossws,
                                                   int n, float* __restrict__ outf) {
  __shared__ float red[256];
  const int tid = threadIdx.x;
  float s = 0.f;
  for (int i = tid; i < n; i += 256) s += lossws[i];
  red[tid] = s;
  __syncthreads();
  for (int w = 128; w > 0; w >>= 1) {
    if (tid < w) red[tid] += red[tid + w];
    __syncthreads();
  }
  if (tid == 0) outf[QOFF + (size_t)NROWTOT * NQ] = red[0] / 16777216.0f;
}

// ---------------- fallback (round-4 passing kernel) ----------------
#define ROWS 32
#define BK 32
#define CP 512
#define TAU 0.05f

__global__ __launch_bounds__(256, 1) void rvq_fb(
    const float* __restrict__ emb, const float* __restrict__ cbg,
    const float* __restrict__ cbsq, float* __restrict__ lossws,
    float* __restrict__ outf) {
  __shared__ float resT[ND][ROWS];
  __shared__ float cc[BK][CP];
  __shared__ int   idx_sh[ROWS];
  __shared__ float wred[4];

  const int tid = threadIdx.x;
  const int wv = tid >> 6, lane = tid & 63;
  const int rg = wv, cg = lane;
  const int n0 = blockIdx.x * ROWS;

  float qacc[64];
  #pragma unroll
  for (int s = 0; s < 64; ++s) qacc[s] = 0.f;

  {
    const int r = tid & 31, db = tid >> 5;
    const float4* src = reinterpret_cast<const float4*>(emb + (size_t)(n0 + r) * ND + db * 64);
    #pragma unroll
    for (int s = 0; s < 16; ++s) {
      float4 v = src[s];
      int d = db * 64 + s * 4;
      resT[d+0][r] = v.x; resT[d+1][r] = v.y; resT[d+2][r] = v.z; resT[d+3][r] = v.w;
    }
  }
  __syncthreads();

  const int c0l = cg * 8;
  const int swm = (c0l >> 6) << 2;
  const int off0 = c0l ^ swm;
  const int off1 = (c0l + 4) ^ swm;

  for (int q = 0; q < NQ; ++q) {
    const float* cbq = cbg + (size_t)q * NC * ND;
    float bd1[8], bd2[8]; int bi1[8], bi2[8];
    #pragma unroll
    for (int j = 0; j < 8; ++j) { bd1[j]=INFINITY; bd2[j]=INFINITY; bi1[j]=0x7fffffff; bi2[j]=0x7fffffff; }

    for (int cp = 0; cp < 2; ++cp) {
      float acc[8][8];
      #pragma unroll
      for (int a = 0; a < 8; ++a)
        #pragma unroll
        for (int b = 0; b < 8; ++b) acc[a][b] = 0.f;

      for (int kc = 0; kc < ND / BK; ++kc) {
        __syncthreads();
        {
          const int half = tid & 1;
          const int k0 = half * 16;
          #pragma unroll
          for (int it = 0; it < 4; ++it) {
            const int c = (tid >> 1) + it * 128;
            const int pc = c ^ ((c >> 6) << 2);
            const float4* src = reinterpret_cast<const float4*>(
                cbq + (size_t)(cp * CP + c) * ND + kc * BK + half * 16);
            float4 v0 = src[0], v1 = src[1], v2 = src[2], v3 = src[3];
            cc[k0+ 0][pc]=v0.x; cc[k0+ 1][pc]=v0.y; cc[k0+ 2][pc]=v0.z; cc[k0+ 3][pc]=v0.w;
            cc[k0+ 4][pc]=v1.x; cc[k0+ 5][pc]=v1.y; cc[k0+ 6][pc]=v1.z; cc[k0+ 7][pc]=v1.w;
            cc[k0+ 8][pc]=v2.x; cc[k0+ 9][pc]=v2.y; cc[k0+10][pc]=v2.z; cc[k0+11][pc]=v2.w;
            cc[k0+12][pc]=v3.x; cc[k0+13][pc]=v3.y; cc[k0+14][pc]=v3.z; cc[k0+15][pc]=v3.w;
          }
        }
        __syncthreads();

        float tmp[8][8];
        #pragma unroll
        for (int a = 0; a < 8; ++a)
          #pragma unroll
          for (int b = 0; b < 8; ++b) tmp[a][b] = 0.f;

        #pragma unroll
        for (int kk = 0; kk < BK; ++kk) {
          const float4* rp = reinterpret_cast<const float4*>(&resT[kc * BK + kk][rg * 8]);
          float4 r0 = rp[0], r1 = rp[1];
          const float* ccrow = &cc[kk][0];
          float4 c0 = *reinterpret_cast<const float4*>(ccrow + off0);
          float4 c1 = *reinterpret_cast<const float4*>(ccrow + off1);
          float rv[8] = {r0.x, r0.y, r0.z, r0.w, r1.x, r1.y, r1.z, r1.w};
          float cv[8] = {c0.x, c0.y, c0.z, c0.w, c1.x, c1.y, c1.z, c1.w};
          #pragma unroll
          for (int a = 0; a < 8; ++a)
            #pragma unroll
            for (int b = 0; b < 8; ++b)
              tmp[a][b] = fmaf(rv[a], cv[b], tmp[a][b]);
        }
        #pragma unroll
        for (int a = 0; a < 8; ++a)
          #pragma unroll
          for (int b = 0; b < 8; ++b) acc[a][b] += tmp[a][b];
      }

      const float4* qp = reinterpret_cast<const float4*>(cbsq + q * NC + cp * CP + cg * 8);
      float4 s0 = qp[0], s1 = qp[1];
      float sqv[8] = {s0.x, s0.y, s0.z, s0.w, s1.x, s1.y, s1.z, s1.w};
      #pragma unroll
      for (int r = 0; r < 8; ++r) {
        float d1 = INFINITY, d2 = INFINITY; int i1 = 0x7fffffff, i2 = 0x7fffffff;
        #pragma unroll
        for (int j = 0; j < 8; ++j) {
          float dd = sqv[j] - 2.0f * acc[r][j];
          merge_in(d1, i1, d2, i2, dd, cp * CP + cg * 8 + j);
        }
        #pragma unroll
        for (int m = 1; m < 64; m <<= 1) {
          float od1 = __shfl_xor(d1, m, 64), od2 = __shfl_xor(d2, m, 64);
          int oi1 = __shfl_xor(i1, m, 64), oi2 = __shfl_xor(i2, m, 64);
          merge_in(d1, i1, d2, i2, od1, oi1);
          merge_in(d1, i1, d2, i2, od2, oi2);
        }
        merge_in(bd1[r], bi1[r], bd2[r], bi2[r], d1, i1);
        merge_in(bd1[r], bi1[r], bd2[r], bi2[r], d2, i2);
      }
    }

    #pragma unroll 1
    for (int r = 0; r < 8; ++r) {
      int fi = bi1[r];
      if (bd2[r] - bd1[r] < TAU) {
        const int row = rg * 8 + r;
        const int ia = bi1[r], ib = bi2[r];
        double da = 0.0, db2 = 0.0;
        #pragma unroll 1
        for (int t = 0; t < 2; ++t) {
          const int cidx = t ? ib : ia;
          const float* cr = cbq + (size_t)cidx * ND;
          double dot = 0.0, ss = 0.0;
          #pragma unroll
          for (int u = 0; u < 8; ++u) {
            int k = lane * 8 + u;
            double cvv = (double)cr[k];
            double rvv = (double)resT[k][row];
            dot += cvv * rvv; ss += cvv * cvv;
          }
          #pragma unroll
          for (int m = 1; m < 64; m <<= 1) { dot += __shfl_xor(dot, m, 64); ss += __shfl_xor(ss, m, 64); }
          double dd = ss - 2.0 * dot;
          if (t) db2 = dd; else da = dd;
        }
        if (db2 < da || (db2 == da && ib < ia)) fi = ib;
      }
      fi = fi < 0 ? 0 : (fi > NC - 1 ? NC - 1 : fi);
      if (lane == 0) {
        idx_sh[rg * 8 + r] = fi;
        outf[QOFF + (size_t)(n0 + rg * 8 + r) * NQ + q] = (float)fi;
      }
    }
    __syncthreads();

    {
      const int r = tid & 31, db = tid >> 5;
      const float* crow = cbq + (size_t)idx_sh[r] * ND;
      float ls = 0.f;
      #pragma unroll
      for (int s = 0; s < 64; ++s) {
        int d = db * 64 + s;
        float cv = crow[d];
        float nv = resT[d][r] - cv;
        resT[d][r] = nv;
        qacc[s] += cv;
        ls += nv * nv;
      }
      #pragma unroll
      for (int m = 1; m < 64; m <<= 1) ls += __shfl_xor(ls, m, 64);
      if (lane == 0) wred[wv] = ls;
    }
    __syncthreads();
    if (tid == 0) lossws[blockIdx.x * NQ + q] = wred[0] + wred[1] + wred[2] + wred[3];
    __syncthreads();
  }

  {
    const int r = tid & 31, db = tid >> 5;
    #pragma unroll
    for (int g = 0; g < 16; ++g) {
      float4 w2;
      w2.x = qacc[g*4+0]; w2.y = qacc[g*4+1]; w2.z = qacc[g*4+2]; w2.w = qacc[g*4+3];
      *reinterpret_cast<float4*>(outf + (size_t)(n0 + r) * ND + db * 64 + g * 4) = w2;
    }
  }
}

extern "C" void kernel_launch(void* const* d_in, const int* in_sizes, int n_in,
                              void* d_out, int out_size, void* d_ws, size_t ws_size,
                              hipStream_t stream) {
  (void)in_sizes; (void)n_in; (void)out_size;
  const float* emb = (const float*)d_in[0];
  const float* cbg = (const float*)d_in[1];
  float* wsf = (float*)d_ws;
  float* outf = (float*)d_out;

  cbsq_kernel<<<256, 256, 0, stream>>>(cbg, wsf);

  if (ws_size >= (size_t)18 * 1024 * 1024) {
    float* lpart = wsf + 8192;                                   // 4096 floats
    unsigned short* Bh = (unsigned short*)((char*)d_ws + 65536); // 8 MB
    unsigned short* Bl = Bh + 4194304;                           // 8 MB
    float* t2d = (float*)((char*)d_ws + 16842752);               // 256 KB
    int*   t2i = (int*)((char*)d_ws + 17104896);                 // 256 KB

    fmt_kernel<<<2048, 256, 0, stream>>>(cbg, Bh, Bl);
    copy_kernel<<<16384, 256, 0, stream>>>((const float4*)emb, (float4*)outf);
    for (int q = 0; q < NQ; ++q) {
      dist_kernel<<<1024, 512, 0, stream>>>(outf, wsf, Bh, Bl, t2d, t2i, q);
      upd_kernel<<<512, 256, 0, stream>>>(outf, emb, cbg, t2d, t2i, lpart, q);
    }
    loss_kernel<<<1, 256, 0, stream>>>(lpart, 4096, outf);
  } else {
    rvq_fb<<<1024, 256, 0, stream>>>(emb, cbg, wsf, wsf + 8192, outf);
    loss_kernel<<<1, 256, 0, stream>>>(wsf + 8192, 8192, outf);
  }
}